// Round 11
// baseline (27.527 us; speedup 1.0000x reference)
//
#include <hip/hip_runtime.h>
#include <hip/hip_bf16.h>

// MoE: out[b] = inp[b] @ weight[gate[b]].T
// inp: [4096,512] f32, gate: [4096] int, weight: [32,512,512] f32, out: [4096,512] f32
// Round 11: W-once design. 256 blocks = (expert, n-tile), 512 threads, BM=256
// (all tokens of the expert) => weight streamed exactly once (32MB compulsory).
// Depth-2 pinned register prefetch (r10's fence, proven) covers HBM latency at
// 1 block/CU. cvt_pk staging + XOR-swizzled LDS + lgkm-only barriers throughout.

#define NE     32
#define NBATCH 4096
#define KF     512
#define NF     512
#define BM     256           // token rows per block (= SROWN cap)
#define BN     64
#define BK     64
#define NKT    (KF / BK)     // 8
#define SROWN  256
#define NCHUNK 64
#define NWG    (NE * 8)      // 256 blocks

typedef __attribute__((ext_vector_type(8))) short bf16x8;
typedef __attribute__((ext_vector_type(4))) float f32x4;

__device__ __forceinline__ unsigned cvt2(float lo, float hi) {
    __hip_bfloat162 h = __float22bfloat162_rn(make_float2(lo, hi));
    return *reinterpret_cast<unsigned*>(&h);   // v_cvt_pk_bf16_f32
}

// XOR swizzle within [row][64 bf16] (128B row stride); same bijection write+read.
__device__ __forceinline__ int swz(int row, int col_b) {
    return (row * 128 + col_b) ^ ((row & 7) << 4);
}

__global__ __launch_bounds__(512, 2)
void moe_fused(const float* __restrict__ inp,
               const int* __restrict__ gate,
               const float* __restrict__ weight,
               float* __restrict__ out) {
    // bijective XCD-chunk swizzle: XCD k owns experts [4k,4k+4) (A rows L2-resident)
    const int bid  = blockIdx.x;
    const int swb  = (bid & 7) * (NWG / 8) + (bid >> 3);
    const int e    = swb >> 3;
    const int nb   = swb & 7;
    const int nblk = nb * BN;

    // LDS: A bf16 [256][64] swizzled (32KB) @0, W bf16 [64][64] (8KB) @32768
    __shared__ __align__(16) unsigned char lds[BM * BK * 2 + BN * BK * 2];
    __shared__ int srow[SROWN];
    __shared__ int chunkinfo[NCHUNK];
    __shared__ int stotal;

    const int tid  = threadIdx.x;
    const int lane = tid & 63;
    const int wid  = tid >> 6;           // 0..7

    // ---- self-prep: ballot-rank tokens of expert e (512-thread form, r8-proven) ----
    int g[8];
#pragma unroll
    for (int i = 0; i < 8; ++i) g[i] = gate[(wid * 8 + i) * 64 + lane];
#pragma unroll
    for (int i = 0; i < 8; ++i) {
        unsigned long long m = __ballot(g[i] == e);
        if (lane == i) chunkinfo[wid * 8 + i] = __popcll(m);
    }
    if (tid < SROWN) srow[tid] = -1;
    __syncthreads();
    if (tid < NCHUNK) {                  // wave 0: scan 64 chunk counts
        int c = chunkinfo[tid];
        int x = c;
#pragma unroll
        for (int d = 1; d < 64; d <<= 1) {
            int u = __shfl_up(x, d, 64);
            if (lane >= d) x += u;
        }
        chunkinfo[tid] = x - c;
        if (tid == NCHUNK - 1) stotal = x;
    }
    __syncthreads();
    const int totalr = stotal;
    if (totalr == 0) return;             // uniform (prob ~0)
#pragma unroll
    for (int i = 0; i < 8; ++i) {
        unsigned long long m = __ballot(g[i] == e);
        int r = chunkinfo[wid * 8 + i] + __popcll(m & ((1ull << lane) - 1ull));
        if (g[i] == e && r < SROWN) srow[r] = (wid * 8 + i) * 64 + lane;
    }
    __syncthreads();

    // ---- staging addresses ----
    // A slots: s = i*512+tid -> row = i*32 + (tid>>4), col4 = (tid&15)*4, i<8
    // W slots: same map, i<2
    int arow[8];
#pragma unroll
    for (int i = 0; i < 8; ++i) arow[i] = srow[i * 32 + (tid >> 4)];

    const float* wbase = weight + (size_t)e * (NF * KF) + (size_t)nblk * KF;
    const float* ap[8];
    const float* wp[2];
#pragma unroll
    for (int i = 0; i < 8; ++i)
        ap[i] = inp + (size_t)(arow[i] < 0 ? 0 : arow[i]) * KF + (tid & 15) * 4;
#pragma unroll
    for (int i = 0; i < 2; ++i)
        wp[i] = wbase + (size_t)(i * 32 + (tid >> 4)) * KF + (tid & 15) * 4;

    float4 ra[2][8], rw[2][2];           // depth-2 banks, static-indexed

#define LOADB(B, T) do { const int k0 = (T) * BK;                                    \
    _Pragma("unroll") for (int i = 0; i < 8; ++i)                                    \
        if (i * 32 < totalr) ra[B][i] = *(const float4*)(ap[i] + k0);                \
    _Pragma("unroll") for (int i = 0; i < 2; ++i)                                    \
        rw[B][i] = *(const float4*)(wp[i] + k0); } while (0)

#define WRITEB(B) do { const int cb = (tid & 15) * 8;                                \
    _Pragma("unroll") for (int i = 0; i < 8; ++i)                                    \
        if (i * 32 < totalr) {                                                       \
            int r = i * 32 + (tid >> 4);                                             \
            uint2 p = make_uint2(cvt2(ra[B][i].x, ra[B][i].y),                       \
                                 cvt2(ra[B][i].z, ra[B][i].w));                      \
            *(uint2*)(lds + swz(r, cb)) = p; }                                       \
    _Pragma("unroll") for (int i = 0; i < 2; ++i) {                                  \
        int r = i * 32 + (tid >> 4);                                                 \
        uint2 p = make_uint2(cvt2(rw[B][i].x, rw[B][i].y),                           \
                             cvt2(rw[B][i].z, rw[B][i].w));                          \
        *(uint2*)(lds + 32768 + swz(r, cb)) = p; } } while (0)

    f32x4 acc[2][4];                     // wave: 32 rows x 64 cols = 2m x 4n frags
#pragma unroll
    for (int mi = 0; mi < 2; ++mi)
#pragma unroll
        for (int ni = 0; ni < 4; ++ni) acc[mi][ni] = (f32x4)(0.f);

    const bool active = (wid * 32) < totalr;

#define COMPUTE() do { if (active) {                                                 \
    _Pragma("unroll") for (int kk = 0; kk < 2; ++kk) {                               \
        const int kb = kk * 64 + 16 * (lane >> 4);                                   \
        bf16x8 af[2], bfr[4];                                                        \
        _Pragma("unroll") for (int mi = 0; mi < 2; ++mi) {                           \
            int r = wid * 32 + mi * 16 + (lane & 15);                                \
            af[mi] = *(const bf16x8*)(lds + swz(r, kb)); }                           \
        _Pragma("unroll") for (int ni = 0; ni < 4; ++ni) {                           \
            int r = ni * 16 + (lane & 15);                                           \
            bfr[ni] = *(const bf16x8*)(lds + 32768 + swz(r, kb)); }                  \
        _Pragma("unroll") for (int mi = 0; mi < 2; ++mi)                             \
        _Pragma("unroll") for (int ni = 0; ni < 4; ++ni)                             \
            acc[mi][ni] = __builtin_amdgcn_mfma_f32_16x16x32_bf16(                   \
                af[mi], bfr[ni], acc[mi][ni], 0, 0, 0); } } } while (0)

    // ---- K-loop: depth-2 pinned prefetch, single LDS buffer, 2 barriers/iter ----
    LOADB(0, 0);
    LOADB(1, 1);
#pragma unroll
    for (int t = 0; t < NKT; ++t) {
        WRITEB(t & 1);                   // compiler inserts counted vmcnt per-use
        asm volatile("s_waitcnt lgkmcnt(0)" ::: "memory");
        __builtin_amdgcn_s_barrier();    // LDS tile t consistent
        if (t + 2 < NKT) LOADB(t & 1, t + 2);  // bank just freed; ~2 iters in flight
        asm volatile("" ::: "memory");   // PIN: loads may not sink below (r10-proven)
        COMPUTE();
        asm volatile("" ::: "memory");
        __builtin_amdgcn_s_barrier();    // reads done before next WRITE
    }
#undef LOADB
#undef WRITEB
#undef COMPUTE

    // ---- epilogue: D frag col=lane&15 (n), row=(lane>>4)*4+q (m) ----
    if (active) {
#pragma unroll
        for (int mi = 0; mi < 2; ++mi)
#pragma unroll
            for (int q = 0; q < 4; ++q) {
                int m = wid * 32 + mi * 16 + (lane >> 4) * 4 + q;
                int row = srow[m];
                if (row >= 0) {
#pragma unroll
                    for (int ni = 0; ni < 4; ++ni)
                        out[(size_t)row * NF + nblk + ni * 16 + (lane & 15)]
                            = acc[mi][ni][q];
                }
            }
    }
}

extern "C" void kernel_launch(void* const* d_in, const int* in_sizes, int n_in,
                              void* d_out, int out_size, void* d_ws, size_t ws_size,
                              hipStream_t stream) {
    const float* inp    = (const float*)d_in[0];
    const int*   gate   = (const int*)d_in[1];
    const float* weight = (const float*)d_in[2];
    float*       out    = (float*)d_out;

    moe_fused<<<NWG, 512, 0, stream>>>(inp, gate, weight, out);
}

// Round 12
// 23.831 us; speedup vs baseline: 1.1551x; 1.1551x over previous
//
#include <hip/hip_runtime.h>
#include <hip/hip_bf16.h>

// MoE: out[b] = inp[b] @ weight[gate[b]].T
// inp: [4096,512] f32, gate: [4096] int, weight: [32,512,512] f32, out: [4096,512] f32
// Round 12: r10 base (best: 21.1us) + three refinements:
//  (1) double-buffer LDS -> ONE barrier per K-step (write buf[t+1] after compute buf[t])
//  (2) depth-2 pinned register prefetch (loads for t+2 issued before COMPUTE(t))
//  (3) W tile-0 loads issued BEFORE prep (only need e; latency drains under ballots)
// Everything else r10-verbatim: ballot-rank prep, cvt_pk staging, XOR swizzle both
// sides, pin fences (r10-proven: without them the compiler sinks every prefetch).

#define NE     32
#define NBATCH 4096
#define KF     512
#define NF     512
#define BM     64
#define BN     64
#define BK     64
#define NKT    (KF / BK)     // 8
#define TMAX   4
#define NCHUNK 64
#define NWG    (8 * NE * TMAX)  // 1024

typedef __attribute__((ext_vector_type(8))) short bf16x8;
typedef __attribute__((ext_vector_type(4))) float f32x4;

__device__ __forceinline__ unsigned cvt2(float lo, float hi) {
    __hip_bfloat162 h = __float22bfloat162_rn(make_float2(lo, hi));
    return *reinterpret_cast<unsigned*>(&h);   // v_cvt_pk_bf16_f32
}

// XOR swizzle within [row][64 bf16] (128B row stride); same bijection write+read.
__device__ __forceinline__ int swz(int row, int col_b) {
    return (row * 128 + col_b) ^ ((row & 7) << 4);
}

__global__ __launch_bounds__(256)
void moe_fused(const float* __restrict__ inp,
               const int* __restrict__ gate,
               const float* __restrict__ weight,
               float* __restrict__ out) {
    // bijective XCD-chunk swizzle (1024 blocks, 8 XCDs): one expert's 32 blocks
    // (4 locals x 8 nb) land on one XCD -> its 4MB W panel stays in that L2.
    const int bid = blockIdx.x;
    const int swb = (bid & 7) * (NWG / 8) + (bid >> 3);
    const int nb    = swb & 7;
    const int y     = swb >> 3;
    const int e     = y >> 2;
    const int local = y & 3;

    __shared__ __align__(16) unsigned char lds[2][(BM + BN) * BK * 2]; // 2 x 16KB
    __shared__ int srow[BM];
    __shared__ int chunkinfo[NCHUNK];
    __shared__ int stotal;

    const int tid  = threadIdx.x;
    const int lane = tid & 63;
    const int wid  = tid >> 6;

    // ---- (3) W tile-0 loads first: need only e; latency hides under prep ----
    const int nblk = nb * BN;
    const float* wbase = weight + (size_t)e * (NF * KF) + (size_t)nblk * KF;
    const int c4 = (tid & 15) * 4;

    float4 ra[2][4], rw[2][4];           // depth-2 banks (static-indexed post-unroll)
#pragma unroll
    for (int i = 0; i < 4; ++i) {
        int r = (tid >> 4) + 16 * i;
        rw[0][i] = *(const float4*)(wbase + (size_t)r * KF + c4);
    }
    asm volatile("" ::: "memory");       // pin: issue now, don't sink into prep

    // ---- self-prep: ballot-rank tokens of expert e (r6/r10-proven) ----
    int g[16];
#pragma unroll
    for (int i = 0; i < 16; ++i)
        g[i] = gate[(wid * 16 + i) * 64 + lane];
#pragma unroll
    for (int i = 0; i < 16; ++i) {
        unsigned long long m = __ballot(g[i] == e);
        if (lane == i) chunkinfo[wid * 16 + i] = __popcll(m);
    }
    if (tid < BM) srow[tid] = -1;
    __syncthreads();
    if (tid < NCHUNK) {
        int c = chunkinfo[tid];
        int x = c;
#pragma unroll
        for (int d = 1; d < 64; d <<= 1) {
            int u = __shfl_up(x, d, 64);
            if (lane >= d) x += u;
        }
        chunkinfo[tid] = x - c;
        if (tid == NCHUNK - 1) stotal = x;
    }
    __syncthreads();

    const int total = stotal;
    const int m0    = local * BM;
    if (m0 >= total) return;             // uniform exit, before any raw s_barrier

#pragma unroll
    for (int i = 0; i < 16; ++i) {
        unsigned long long m = __ballot(g[i] == e);
        int r = chunkinfo[wid * 16 + i] + __popcll(m & ((1ull << lane) - 1ull));
        if (g[i] == e && r >= m0 && r < m0 + BM)
            srow[r - m0] = (wid * 16 + i) * 64 + lane;
    }
    __syncthreads();

    const int wm = wid & 1;
    const int wn = wid >> 1;

    int arow[4];
    const float* ap[4];
#pragma unroll
    for (int i = 0; i < 4; ++i) {
        arow[i] = srow[(tid >> 4) + 16 * i];
        ap[i] = inp + (size_t)(arow[i] < 0 ? 0 : arow[i]) * KF + c4;
    }

#define LOADA(B, T) do { const int k0 = (T) * BK;                                    \
    _Pragma("unroll") for (int i = 0; i < 4; ++i)                                    \
        ra[B][i] = (arow[i] >= 0) ? *(const float4*)(ap[i] + k0)                     \
                                  : make_float4(0.f, 0.f, 0.f, 0.f); } while (0)

#define LOADW(B, T) do { const int k0 = (T) * BK;                                    \
    _Pragma("unroll") for (int i = 0; i < 4; ++i) {                                  \
        int r = (tid >> 4) + 16 * i;                                                 \
        rw[B][i] = *(const float4*)(wbase + (size_t)r * KF + k0 + c4); } } while (0)

#define WRITE_T(LB, B) do { const int cb = (tid & 15) * 8;                           \
    unsigned char* Lb = lds[LB];                                                     \
    _Pragma("unroll") for (int i = 0; i < 4; ++i) {                                  \
        int r = (tid >> 4) + 16 * i;                                                 \
        uint2 p = make_uint2(cvt2(ra[B][i].x, ra[B][i].y),                           \
                             cvt2(ra[B][i].z, ra[B][i].w));                          \
        *(uint2*)(Lb + swz(r, cb)) = p; }                                            \
    _Pragma("unroll") for (int i = 0; i < 4; ++i) {                                  \
        int r = (tid >> 4) + 16 * i;                                                 \
        uint2 p = make_uint2(cvt2(rw[B][i].x, rw[B][i].y),                           \
                             cvt2(rw[B][i].z, rw[B][i].w));                          \
        *(uint2*)(Lb + 8192 + swz(r, cb)) = p; } } while (0)

    f32x4 acc[2][2];
#pragma unroll
    for (int mi = 0; mi < 2; ++mi)
#pragma unroll
        for (int ni = 0; ni < 2; ++ni) acc[mi][ni] = (f32x4)(0.f);

#define COMPUTE_T(LB) do { const unsigned char* Lb = lds[LB];                        \
    _Pragma("unroll") for (int kk = 0; kk < 2; ++kk) {                               \
        const int kb = kk * 64 + 16 * (lane >> 4);                                   \
        bf16x8 af[2], bfr[2];                                                        \
        _Pragma("unroll") for (int mi = 0; mi < 2; ++mi) {                           \
            int r = wm * 32 + mi * 16 + (lane & 15);                                 \
            af[mi] = *(const bf16x8*)(Lb + swz(r, kb)); }                            \
        _Pragma("unroll") for (int ni = 0; ni < 2; ++ni) {                           \
            int r = wn * 32 + ni * 16 + (lane & 15);                                 \
            bfr[ni] = *(const bf16x8*)(Lb + 8192 + swz(r, kb)); }                    \
        _Pragma("unroll") for (int mi = 0; mi < 2; ++mi)                             \
        _Pragma("unroll") for (int ni = 0; ni < 2; ++ni)                             \
            acc[mi][ni] = __builtin_amdgcn_mfma_f32_16x16x32_bf16(                   \
                af[mi], bfr[ni], acc[mi][ni], 0, 0, 0); } } while (0)

    // ---- prologue: stage tile 0 into lds0; tile-1 loads in flight ----
    LOADA(0, 0);
    LOADA(1, 1);
    LOADW(1, 1);
    asm volatile("" ::: "memory");       // pin all prologue loads above WRITE
    WRITE_T(0, 0);                       // waits vmcnt for bank 0 only (per-reg)
    asm volatile("s_waitcnt lgkmcnt(0)" ::: "memory");
    __builtin_amdgcn_s_barrier();        // lds0 ready

    // ---- steady state: ONE barrier per K-step, depth-2 in flight ----
#pragma unroll
    for (int t = 0; t < NKT; ++t) {
        if (t + 2 < NKT) {               // bank (t&1) just freed last iteration
            LOADA(t & 1, t + 2);
            LOADW(t & 1, t + 2);
        }
        asm volatile("" ::: "memory");   // pin: loads may not sink below (r10-proven)
        COMPUTE_T(t & 1);                // tile t from lds[t&1]
        if (t + 1 < NKT) {
            WRITE_T((t + 1) & 1, (t + 1) & 1);  // stage tile t+1 into other buffer
            asm volatile("s_waitcnt lgkmcnt(0)" ::: "memory");
            __builtin_amdgcn_s_barrier();       // lds[(t+1)&1] ready for next iter
        }
    }
#undef LOADA
#undef LOADW
#undef WRITE_T
#undef COMPUTE_T

    // ---- epilogue: D frag col=lane&15 (n), row=(lane>>4)*4+q (m) ----
#pragma unroll
    for (int mi = 0; mi < 2; ++mi)
#pragma unroll
        for (int q = 0; q < 4; ++q) {
            int m = wm * 32 + mi * 16 + (lane >> 4) * 4 + q;
            int row = srow[m];
            if (row >= 0) {
#pragma unroll
                for (int ni = 0; ni < 2; ++ni)
                    out[(size_t)row * NF + nblk + wn * 32 + ni * 16 + (lane & 15)]
                        = acc[mi][ni][q];
            }
        }
}

extern "C" void kernel_launch(void* const* d_in, const int* in_sizes, int n_in,
                              void* d_out, int out_size, void* d_ws, size_t ws_size,
                              hipStream_t stream) {
    const float* inp    = (const float*)d_in[0];
    const int*   gate   = (const int*)d_in[1];
    const float* weight = (const float*)d_in[2];
    float*       out    = (float*)d_out;

    moe_fused<<<NWG, 256, 0, stream>>>(inp, gate, weight, out);
}

// Round 13
// 19.204 us; speedup vs baseline: 1.4334x; 1.2409x over previous
//
#include <hip/hip_runtime.h>
#include <hip/hip_bf16.h>

// MoE: out[b] = inp[b] @ weight[gate[b]].T
// inp: [4096,512] f32, gate: [4096] int, weight: [32,512,512] f32, out: [4096,512] f32
// Round 13: r10 (best, 21.1us) with BK=128 (NKT=4): half the barriers and vmcnt
// drains; COMPUTE (16 MFMA + 16 ds_read_b128) now fully covers depth-1 load
// latency. W tile-0 issued before prep (hides under ballots). Pin fences kept
// (r10-proven); depth stays 1 (r12: depth-2 + memory-clobber pins = forced drain).

#define NE     32
#define NBATCH 4096
#define KF     512
#define NF     512
#define BM     64
#define BN     64
#define BK     128
#define NKT    (KF / BK)     // 4
#define TMAX   4
#define NCHUNK 64
#define NWG    (8 * NE * TMAX)  // 1024

typedef __attribute__((ext_vector_type(8))) short bf16x8;
typedef __attribute__((ext_vector_type(4))) float f32x4;

__device__ __forceinline__ unsigned cvt2(float lo, float hi) {
    __hip_bfloat162 h = __float22bfloat162_rn(make_float2(lo, hi));
    return *reinterpret_cast<unsigned*>(&h);   // v_cvt_pk_bf16_f32
}

// XOR swizzle within [row][128 bf16] (256B row stride); same bijection write+read.
// Read: lanes 0-15 span rows 0-15 at same kb -> 8 distinct 16B slots -> 2-way (free).
__device__ __forceinline__ int swz(int row, int col_b) {
    return (row * 256 + col_b) ^ ((row & 7) << 4);
}

__global__ __launch_bounds__(256)
void moe_fused(const float* __restrict__ inp,
               const int* __restrict__ gate,
               const float* __restrict__ weight,
               float* __restrict__ out) {
    // bijective XCD-chunk swizzle (1024 blocks, 8 XCDs)
    const int bid = blockIdx.x;
    const int swb = (bid & 7) * (NWG / 8) + (bid >> 3);
    const int nb    = swb & 7;
    const int y     = swb >> 3;
    const int e     = y >> 2;
    const int local = y & 3;

    __shared__ __align__(16) unsigned char lds[(BM + BN) * BK * 2]; // 32KB single buf
    __shared__ int srow[BM];
    __shared__ int chunkinfo[NCHUNK];
    __shared__ int stotal;

    const int tid  = threadIdx.x;
    const int lane = tid & 63;
    const int wid  = tid >> 6;

    // staging map: slot s = i*256+tid -> row = (tid>>5) + 8*i, col4 = (tid&31)*4
    const int srow_i = tid >> 5;
    const int c4     = (tid & 31) * 4;
    const int nblk   = nb * BN;
    const float* wbase = weight + (size_t)e * (NF * KF) + (size_t)nblk * KF;

    float4 ra[8], rw[8];

    // ---- W tile-0 issued BEFORE prep: only needs e; ~600cy hides under ballots ----
#pragma unroll
    for (int i = 0; i < 8; ++i) {
        int r = srow_i + 8 * i;
        rw[i] = *(const float4*)(wbase + (size_t)r * KF + c4);
    }
    asm volatile("" ::: "memory");       // pin: issue now, don't sink into prep

    // ---- self-prep: ballot-rank tokens of expert e (r6/r10-proven) ----
    int g[16];
#pragma unroll
    for (int i = 0; i < 16; ++i)
        g[i] = gate[(wid * 16 + i) * 64 + lane];
#pragma unroll
    for (int i = 0; i < 16; ++i) {
        unsigned long long m = __ballot(g[i] == e);
        if (lane == i) chunkinfo[wid * 16 + i] = __popcll(m);
    }
    if (tid < BM) srow[tid] = -1;
    __syncthreads();
    if (tid < NCHUNK) {
        int c = chunkinfo[tid];
        int x = c;
#pragma unroll
        for (int d = 1; d < 64; d <<= 1) {
            int u = __shfl_up(x, d, 64);
            if (lane >= d) x += u;
        }
        chunkinfo[tid] = x - c;
        if (tid == NCHUNK - 1) stotal = x;
    }
    __syncthreads();

    const int total = stotal;
    const int m0    = local * BM;
    if (m0 >= total) return;             // uniform exit before any raw s_barrier

#pragma unroll
    for (int i = 0; i < 16; ++i) {
        unsigned long long m = __ballot(g[i] == e);
        int r = chunkinfo[wid * 16 + i] + __popcll(m & ((1ull << lane) - 1ull));
        if (g[i] == e && r >= m0 && r < m0 + BM)
            srow[r - m0] = (wid * 16 + i) * 64 + lane;
    }
    __syncthreads();

    const int wm = wid & 1;
    const int wn = wid >> 1;

    int arow[8];
    const float* ap[8];
#pragma unroll
    for (int i = 0; i < 8; ++i) {
        arow[i] = srow[srow_i + 8 * i];
        ap[i] = inp + (size_t)(arow[i] < 0 ? 0 : arow[i]) * KF + c4;
    }

#define LOADA(T) do { const int k0 = (T) * BK;                                       \
    _Pragma("unroll") for (int i = 0; i < 8; ++i)                                    \
        ra[i] = (arow[i] >= 0) ? *(const float4*)(ap[i] + k0)                        \
                               : make_float4(0.f, 0.f, 0.f, 0.f); } while (0)

#define LOADW(T) do { const int k0 = (T) * BK;                                       \
    _Pragma("unroll") for (int i = 0; i < 8; ++i) {                                  \
        int r = srow_i + 8 * i;                                                      \
        rw[i] = *(const float4*)(wbase + (size_t)r * KF + k0 + c4); } } while (0)

#define WRITE_TILE() do { const int cb = (tid & 31) * 8;                             \
    _Pragma("unroll") for (int i = 0; i < 8; ++i) {                                  \
        int r = srow_i + 8 * i;                                                      \
        uint2 p = make_uint2(cvt2(ra[i].x, ra[i].y), cvt2(ra[i].z, ra[i].w));        \
        *(uint2*)(lds + swz(r, cb)) = p; }                                           \
    _Pragma("unroll") for (int i = 0; i < 8; ++i) {                                  \
        int r = srow_i + 8 * i;                                                      \
        uint2 p = make_uint2(cvt2(rw[i].x, rw[i].y), cvt2(rw[i].z, rw[i].w));        \
        *(uint2*)(lds + 16384 + swz(r, cb)) = p; } } while (0)

    f32x4 acc[2][2];
#pragma unroll
    for (int mi = 0; mi < 2; ++mi)
#pragma unroll
        for (int ni = 0; ni < 2; ++ni) acc[mi][ni] = (f32x4)(0.f);

#define COMPUTE() do {                                                               \
    _Pragma("unroll") for (int kk = 0; kk < 4; ++kk) {                               \
        const int kb = kk * 64 + 16 * (lane >> 4);                                   \
        bf16x8 af[2], bfr[2];                                                        \
        _Pragma("unroll") for (int mi = 0; mi < 2; ++mi) {                           \
            int r = wm * 32 + mi * 16 + (lane & 15);                                 \
            af[mi] = *(const bf16x8*)(lds + swz(r, kb)); }                           \
        _Pragma("unroll") for (int ni = 0; ni < 2; ++ni) {                           \
            int r = wn * 32 + ni * 16 + (lane & 15);                                 \
            bfr[ni] = *(const bf16x8*)(lds + 16384 + swz(r, kb)); }                  \
        _Pragma("unroll") for (int mi = 0; mi < 2; ++mi)                             \
        _Pragma("unroll") for (int ni = 0; ni < 2; ++ni)                             \
            acc[mi][ni] = __builtin_amdgcn_mfma_f32_16x16x32_bf16(                   \
                af[mi], bfr[ni], acc[mi][ni], 0, 0, 0); } } while (0)

    // ---- K-loop (r10 schedule, NKT=4): loads for t+1 pinned above COMPUTE(t) ----
    LOADA(0);                            // W tile 0 already in flight since entry
    for (int t = 0; t < NKT; ++t) {
        WRITE_TILE();                    // per-use vmcnt: waits current-tile loads only
        asm volatile("s_waitcnt lgkmcnt(0)" ::: "memory");
        __builtin_amdgcn_s_barrier();    // LDS tile t consistent
        if (t + 1 < NKT) {
            LOADA(t + 1);
            LOADW(t + 1);
        }
        asm volatile("" ::: "memory");   // PIN: loads may not sink below (r10-proven)
        COMPUTE();                       // 16 MFMA + 16 ds_read cover load latency
        asm volatile("" ::: "memory");
        __builtin_amdgcn_s_barrier();    // all reads done before next WRITE
        asm volatile("" ::: "memory");
    }
#undef LOADA
#undef LOADW
#undef WRITE_TILE
#undef COMPUTE

    // ---- epilogue: D frag col=lane&15 (n), row=(lane>>4)*4+q (m) ----
#pragma unroll
    for (int mi = 0; mi < 2; ++mi)
#pragma unroll
        for (int q = 0; q < 4; ++q) {
            int m = wm * 32 + mi * 16 + (lane >> 4) * 4 + q;
            int row = srow[m];
            if (row >= 0) {
#pragma unroll
                for (int ni = 0; ni < 2; ++ni)
                    out[(size_t)row * NF + nblk + wn * 32 + ni * 16 + (lane & 15)]
                        = acc[mi][ni][q];
            }
        }
}

extern "C" void kernel_launch(void* const* d_in, const int* in_sizes, int n_in,
                              void* d_out, int out_size, void* d_ws, size_t ws_size,
                              hipStream_t stream) {
    const float* inp    = (const float*)d_in[0];
    const int*   gate   = (const int*)d_in[1];
    const float* weight = (const float*)d_in[2];
    float*       out    = (float*)d_out;

    moe_fused<<<NWG, 256, 0, stream>>>(inp, gate, weight, out);
}